// Round 10
// baseline (30.291 us; speedup 1.0000x reference)
//
#include <hip/hip_runtime.h>
#include <math.h>

#define BB 32
#define MM 256
#define H2 32
#define NOUT 8

// sinh(t) up to sign (caller squares it). Series keeps relative accuracy for
// small t; exp formula for |t| >= 0.5.
__device__ __forceinline__ float sinh_mag(float t) {
    float a  = fabsf(t);
    float e  = __expf(a);
    float big = 0.5f * (e - __builtin_amdgcn_rcpf(e));
    float t2 = t * t;
    float small = t + t * t2 * (1.0f/6.0f + t2 * (1.0f/120.0f));
    return (a < 0.5f) ? small : big;
}

// sin(t) up to sign (caller squares it). Series for small t avoids the
// cos-cancellation region; hw sin elsewhere.
__device__ __forceinline__ float sin_mag(float t) {
    float a  = fabsf(t);
    float t2 = t * t;
    float small = t + t * t2 * (-1.0f/6.0f + t2 * (1.0f/120.0f));
    float big = __sinf(t);
    return (a < 0.5f) ? small : big;
}

__global__ __launch_bounds__(256) void interaction_kernel(
    const float* __restrict__ x, const int* __restrict__ mask,
    const float* __restrict__ W1, const float* __restrict__ b1,
    const float* __restrict__ W2, const float* __restrict__ b2,
    float* __restrict__ out)
{
    // 32 KB staging tile: [p][ii][j]  (index = p*1024 + ii*256 + j)
    __shared__ float tile[NOUT * 4 * MM];

    // 2048 blocks; XCD-chunked swizzle (2048 % 8 == 0, bijective)
    const int bid = blockIdx.x;
    const int nb  = (bid & 7) * 256 + (bid >> 3);
    const int b   = nb >> 6;               // batch
    const int i0  = (nb & 63) << 2;        // 4 consecutive i-rows
    const int t   = threadIdx.x;           // j index

    // j-side: hoisted (shared by all 4 rows)
    const float eta_j = x[(b * MM + t) * 3 + 0];
    const float phi_j = x[(b * MM + t) * 3 + 1];
    const float lpt_j = x[(b * MM + t) * 3 + 2];
    const float mf    = mask[b * MM + t] ? 1.f : 0.f;

    #pragma unroll 4
    for (int ii = 0; ii < 4; ++ii) {
        const int i  = i0 + ii;
        const int mi = mask[b * MM + i];          // uniform -> scalar

        if (mi == 0) {
            #pragma unroll
            for (int p = 0; p < NOUT; ++p)
                tile[p * 1024 + ii * 256 + t] = 0.f;
            continue;
        }

        // i-side (uniform -> scalar loads)
        const float eta_i = x[(b * MM + i) * 3 + 0];
        const float phi_i = x[(b * MM + i) * 3 + 1];
        const float lpt_i = x[(b * MM + i) * 3 + 2];

        const float dx  = eta_i - eta_j;
        const float dy  = phi_i - phi_j;
        const float dr2 = dx * dx + dy * dy;

        const float L   = (dr2 > 0.f) ? 0.5f * __logf(dr2) : 0.f;
        const float fdr = L;
        const float fkt = (dr2 > 0.f) ? fminf(lpt_i, lpt_j) + L : 0.f;

        // cosh(dx) - cos(dy) = 2*(sinh^2(dx/2) + sin^2(dy/2)) (cancellation-free)
        const float sh = sinh_mag(0.5f * dx);
        const float sn = sin_mag(0.5f * dy);
        const float c  = 2.0f * (sh * sh + sn * sn);
        const float fmass = (c > 0.f) ? __logf(2.0f * c) + lpt_i + lpt_j : 0.f;

        float o[NOUT];
        #pragma unroll
        for (int p = 0; p < NOUT; ++p) o[p] = b2[p];

        #pragma unroll
        for (int k = 0; k < H2; ++k) {
            float z = b1[k];
            z = fmaf(fmass, W1[k * 3 + 0], z);
            z = fmaf(fdr,   W1[k * 3 + 1], z);
            z = fmaf(fkt,   W1[k * 3 + 2], z);
            z = (z >= 0.f) ? z : 0.01f * z;   // leaky_relu
            #pragma unroll
            for (int p = 0; p < NOUT; ++p)
                o[p] = fmaf(z, W2[p * H2 + k], o[p]);
        }

        #pragma unroll
        for (int p = 0; p < NOUT; ++p)
            tile[p * 1024 + ii * 256 + t] = o[p] * mf;
    }

    __syncthreads();

    // store: per plane one 4 KB contiguous burst (1 float4 per thread)
    float4* out4 = (float4*)out;
    const float4* t4 = (const float4*)tile;
    #pragma unroll
    for (int p = 0; p < NOUT; ++p)
        out4[(size_t)(b * NOUT + p) * (MM * MM / 4) + i0 * (MM / 4) + t] =
            t4[p * 256 + t];
}

extern "C" void kernel_launch(void* const* d_in, const int* in_sizes, int n_in,
                              void* d_out, int out_size, void* d_ws, size_t ws_size,
                              hipStream_t stream) {
    const float* x    = (const float*)d_in[0];
    const int*   mask = (const int*)d_in[1];
    const float* W1   = (const float*)d_in[2];
    const float* b1   = (const float*)d_in[3];
    const float* W2   = (const float*)d_in[4];
    const float* b2   = (const float*)d_in[5];
    float* out = (float*)d_out;

    dim3 grid(BB * MM / 4);
    dim3 block(MM);
    interaction_kernel<<<grid, block, 0, stream>>>(x, mask, W1, b1, W2, b2, out);
}

// Round 11
// 21.368 us; speedup vs baseline: 1.4176x; 1.4176x over previous
//
#include <hip/hip_runtime.h>
#include <math.h>

#define BB 32
#define MM 256
#define H2 32
#define NOUT 8

typedef float v2f __attribute__((ext_vector_type(2)));

// sinh(t) up to sign (caller squares it). Series keeps relative accuracy for
// small t; exp formula for |t| >= 0.5.
__device__ __forceinline__ float sinh_mag(float t) {
    float a  = fabsf(t);
    float e  = __expf(a);
    float big = 0.5f * (e - __builtin_amdgcn_rcpf(e));
    float t2 = t * t;
    float small = t + t * t2 * (1.0f/6.0f + t2 * (1.0f/120.0f));
    return (a < 0.5f) ? small : big;
}

// sin(t) up to sign (caller squares it). Series for small t avoids the
// cos-cancellation region; hw sin elsewhere.
__device__ __forceinline__ float sin_mag(float t) {
    float a  = fabsf(t);
    float t2 = t * t;
    float small = t + t * t2 * (-1.0f/6.0f + t2 * (1.0f/120.0f));
    float big = __sinf(t);
    return (a < 0.5f) ? small : big;
}

__global__ __launch_bounds__(256) void interaction_kernel(
    const float* __restrict__ x, const int* __restrict__ mask,
    const float* __restrict__ W1, const float* __restrict__ b1,
    const float* __restrict__ W2, const float* __restrict__ b2,
    float* __restrict__ out)
{
    // XCD-chunked swizzle: 8192 blocks, 8 XCDs
    const int bid = blockIdx.x;
    const int nb  = (bid & 7) * 1024 + (bid >> 3);
    const int b   = nb >> 8;
    const int i   = nb & 255;
    const int t   = threadIdx.x;      // j index

    float* op = out + ((size_t)(b * NOUT)) * (MM * MM) + (size_t)i * MM + t;
    const int PSTRIDE = MM * MM;

    const int mi = mask[b * MM + i];  // block-uniform
    if (mi == 0) {
        #pragma unroll
        for (int p = 0; p < NOUT; ++p)
            __builtin_nontemporal_store(0.f, op + p * PSTRIDE);
        return;
    }

    // i-side (block-uniform -> scalar loads)
    const float eta_i = x[(b * MM + i) * 3 + 0];
    const float phi_i = x[(b * MM + i) * 3 + 1];
    const float lpt_i = x[(b * MM + i) * 3 + 2];

    // j-side per-thread
    const float eta_j = x[(b * MM + t) * 3 + 0];
    const float phi_j = x[(b * MM + t) * 3 + 1];
    const float lpt_j = x[(b * MM + t) * 3 + 2];
    const float mf    = mask[b * MM + t] ? 1.f : 0.f;

    const float dx  = eta_i - eta_j;
    const float dy  = phi_i - phi_j;
    const float dr2 = dx * dx + dy * dy;

    const float L   = (dr2 > 0.f) ? 0.5f * __logf(dr2) : 0.f;
    const float fdr = L;
    const float fkt = (dr2 > 0.f) ? fminf(lpt_i, lpt_j) + L : 0.f;

    // cosh(dx) - cos(dy) = 2*(sinh^2(dx/2) + sin^2(dy/2)) (cancellation-free)
    const float sh = sinh_mag(0.5f * dx);
    const float sn = sin_mag(0.5f * dy);
    const float c  = 2.0f * (sh * sh + sn * sn);
    const float fmass = (c > 0.f) ? __logf(2.0f * c) + lpt_i + lpt_j : 0.f;

    // ---- packed-f32 MLP (v_pk_fma_f32): layer 1 packed over k-pairs ----
    const v2f fmass2 = (v2f)(fmass);
    const v2f fdr2   = (v2f)(fdr);
    const v2f fkt2   = (v2f)(fkt);
    const v2f zero2  = (v2f)(0.f);

    v2f z2[H2 / 2];
    #pragma unroll
    for (int m = 0; m < H2 / 2; ++m) {
        // uniform weight pairs (column c of rows 2m, 2m+1)
        v2f w0, w1, w2, bb;
        w0.x = W1[(2 * m) * 3 + 0]; w0.y = W1[(2 * m + 1) * 3 + 0];
        w1.x = W1[(2 * m) * 3 + 1]; w1.y = W1[(2 * m + 1) * 3 + 1];
        w2.x = W1[(2 * m) * 3 + 2]; w2.y = W1[(2 * m + 1) * 3 + 2];
        bb   = *(const v2f*)(b1 + 2 * m);       // adjacent -> one s_load
        v2f tt = bb;
        tt = __builtin_elementwise_fma(fmass2, w0, tt);
        tt = __builtin_elementwise_fma(fdr2,   w1, tt);
        tt = __builtin_elementwise_fma(fkt2,   w2, tt);
        // leaky_relu == max(t,0) + 0.01*min(t,0) (exact)
        z2[m] = __builtin_elementwise_fma(
                    (v2f)(0.01f), __builtin_elementwise_min(tt, zero2),
                    __builtin_elementwise_max(tt, zero2));
    }

    // layer 2: packed accumulators per p over k-pairs (adjacent weight pairs)
    v2f opk[NOUT];
    #pragma unroll
    for (int p = 0; p < NOUT; ++p) { opk[p].x = b2[p]; opk[p].y = 0.f; }

    #pragma unroll
    for (int m = 0; m < H2 / 2; ++m) {
        #pragma unroll
        for (int p = 0; p < NOUT; ++p) {
            const v2f wv = *(const v2f*)(W2 + p * H2 + 2 * m);  // s_load_dwordx2
            opk[p] = __builtin_elementwise_fma(z2[m], wv, opk[p]);
        }
    }

    #pragma unroll
    for (int p = 0; p < NOUT; ++p)
        __builtin_nontemporal_store((opk[p].x + opk[p].y) * mf, op + p * PSTRIDE);
}

extern "C" void kernel_launch(void* const* d_in, const int* in_sizes, int n_in,
                              void* d_out, int out_size, void* d_ws, size_t ws_size,
                              hipStream_t stream) {
    const float* x    = (const float*)d_in[0];
    const int*   mask = (const int*)d_in[1];
    const float* W1   = (const float*)d_in[2];
    const float* b1   = (const float*)d_in[3];
    const float* W2   = (const float*)d_in[4];
    const float* b2   = (const float*)d_in[5];
    float* out = (float*)d_out;

    dim3 grid(BB * MM);
    dim3 block(MM);
    interaction_kernel<<<grid, block, 0, stream>>>(x, mask, W1, b1, W2, b2, out);
}